// Round 4
// baseline (238.849 us; speedup 1.0000x reference)
//
#include <hip/hip_runtime.h>
#include <stdint.h>

typedef unsigned long long u64;
typedef unsigned int u32;

#define NB 8
#define NN 2048
#define NC 80
#define ROW 84
#define OUT_K 200
#define IOU_T 0.5f
#define SCORE_T 0.01f
#define TGT 896
#define POOL 1024

// ---- compare-exchange, descending network, direction from global index ----
__device__ __forceinline__ void ce_desc(u64* a, int i, int j, int k) {
    u64 a0 = a[i], a1 = a[i + j];
    bool up = ((i & k) == 0);
    if (up ? (a0 < a1) : (a0 > a1)) { a[i] = a1; a[i + j] = a0; }
}

// register compare-exchange; up=true -> larger first (descending pair)
__device__ __forceinline__ void ceg(u64& x, u64& y, bool up) {
    u64 a0 = x, a1 = y;
    if (up ? (a0 < a1) : (a0 > a1)) { x = a1; y = a0; }
}

// wave-local rounds on a 512-elem segment (4 CE/lane/round), j<=256
__device__ __forceinline__ void wave_rounds512(u64* a, int base, int k, int jhi, int lane) {
    for (int j = jhi; j > 0; j >>= 1) {
        #pragma unroll
        for (int p = 0; p < 4; p++) {
            int r = lane + p * 64;
            int low = r & (j - 1);
            int high = (r & ~(j - 1)) << 1;
            ce_desc(a, base + (high | low), j, k);
        }
        __builtin_amdgcn_wave_barrier();
    }
}

// wave-local rounds on a 256-elem segment; k=0x40000000 -> all-descending merge
__device__ __forceinline__ void wave_rounds256(u64* a, int base, int k, int jhi, int lane) {
    for (int j = jhi; j > 0; j >>= 1) {
        #pragma unroll
        for (int p = 0; p < 2; p++) {
            int r = lane + p * 64;
            int low = r & (j - 1);
            int high = (r & ~(j - 1)) << 1;
            ce_desc(a, base + (high | low), j, k);
        }
        __builtin_amdgcn_wave_barrier();
    }
}

// max-combine two desc-sorted 256-runs (base, base+off) -> top-256 sorted desc
__device__ __forceinline__ void pair_merge256(u64* a, int base, int off, int lane) {
    #pragma unroll
    for (int p0 = 0; p0 < 4; p0++) {
        int p = lane + p0 * 64;
        u64 xv = a[base + p];
        u64 yv = a[base + off + 255 - p];
        a[base + p] = xv > yv ? xv : yv;
    }
    __builtin_amdgcn_wave_barrier();
    wave_rounds256(a, base, 0x40000000, 128, lane);
}

// full hybrid bitonic sort of 2048 (desc), 512-thread version.
// Identical CE network to the verified 256-thread version: block-level
// rounds use 512 threads (1-2 CE each), wave-local rounds run on waves 0-3.
__device__ __forceinline__ void sort2048(u64* key, int tid, int lane, int wv) {
    if (wv < 4) {
        const int base = wv * 512;
        for (int k = 2; k <= 512; k <<= 1)
            wave_rounds512(key, base, k, k >> 1, lane);
    }
    __syncthreads();
    #pragma unroll
    for (int p = 0; p < 2; p++) {
        int r = tid + p * 512;
        int low = r & 511, high = (r & ~511) << 1;
        ce_desc(key, high | low, 512, 1024);
    }
    __syncthreads();
    if (wv < 4) wave_rounds512(key, wv * 512, 1024, 256, lane);
    __syncthreads();
    #pragma unroll
    for (int p = 0; p < 2; p++) {
        int r = tid + p * 512;
        int low = r & 1023, high = (r & ~1023) << 1;
        ce_desc(key, high | low, 1024, 2048);
    }
    __syncthreads();
    #pragma unroll
    for (int p = 0; p < 2; p++) {
        int r = tid + p * 512;
        int low = r & 511, high = (r & ~511) << 1;
        ce_desc(key, high | low, 512, 2048);
    }
    __syncthreads();
    if (wv < 4) wave_rounds512(key, wv * 512, 2048, 256, lane);
    __syncthreads();
}

// bitonic sort of 1024 (desc), 512-thread version. Wave-local + fused
// register rounds run on waves 0-3 (tid<256, 4 elems/thread, verbatim
// network); the block-level j>=256 rounds are redistributed to 512 threads.
__device__ __forceinline__ void sort1024(u64* a, int tid, int lane, int wv) {
    if (wv < 4) {
        const int t4 = tid * 4;
        const int sb = wv * 256;
        {
            u64 v0 = a[t4], v1 = a[t4 + 1], v2 = a[t4 + 2], v3 = a[t4 + 3];
            ceg(v0, v1, true);
            ceg(v2, v3, false);
            const bool d4 = ((t4 & 4) == 0);
            ceg(v0, v2, d4); ceg(v1, v3, d4);
            ceg(v0, v1, d4); ceg(v2, v3, d4);
            a[t4] = v0; a[t4 + 1] = v1; a[t4 + 2] = v2; a[t4 + 3] = v3;
        }
        __builtin_amdgcn_wave_barrier();
        for (int k = 8; k <= 256; k <<= 1) {
            for (int j = k >> 1; j >= 4; j >>= 1) {
                #pragma unroll
                for (int p = 0; p < 2; p++) {
                    int r = lane + p * 64;
                    int low = r & (j - 1);
                    int high = (r & ~(j - 1)) << 1;
                    ce_desc(a, sb + (high | low), j, k);
                }
                __builtin_amdgcn_wave_barrier();
            }
            {
                u64 v0 = a[t4], v1 = a[t4 + 1], v2 = a[t4 + 2], v3 = a[t4 + 3];
                const bool d = ((t4 & k) == 0);
                ceg(v0, v2, d); ceg(v1, v3, d);
                ceg(v0, v1, d); ceg(v2, v3, d);
                a[t4] = v0; a[t4 + 1] = v1; a[t4 + 2] = v2; a[t4 + 3] = v3;
            }
            __builtin_amdgcn_wave_barrier();
        }
    }
    __syncthreads();
    {
        int r = tid;
        int low = r & 255, high = (r & ~255) << 1;
        ce_desc(a, high | low, 256, 512);
    }
    __syncthreads();
    if (wv < 4) {
        const int t4 = tid * 4;
        const int sb = wv * 256;
        for (int j = 128; j >= 4; j >>= 1) {
            #pragma unroll
            for (int p = 0; p < 2; p++) {
                int r = lane + p * 64;
                int low = r & (j - 1);
                int high = (r & ~(j - 1)) << 1;
                ce_desc(a, sb + (high | low), j, 512);
            }
            __builtin_amdgcn_wave_barrier();
        }
        {
            u64 v0 = a[t4], v1 = a[t4 + 1], v2 = a[t4 + 2], v3 = a[t4 + 3];
            const bool d = ((t4 & 512) == 0);
            ceg(v0, v2, d); ceg(v1, v3, d);
            ceg(v0, v1, d); ceg(v2, v3, d);
            a[t4] = v0; a[t4 + 1] = v1; a[t4 + 2] = v2; a[t4 + 3] = v3;
        }
    }
    __syncthreads();
    {
        int r = tid;
        int low = r & 511, high = (r & ~511) << 1;
        ce_desc(a, high | low, 512, 1024);
    }
    __syncthreads();
    {
        int r = tid;
        int low = r & 255, high = (r & ~255) << 1;
        ce_desc(a, high | low, 256, 1024);
    }
    __syncthreads();
    if (wv < 4) {
        const int t4 = tid * 4;
        const int sb = wv * 256;
        for (int j = 128; j >= 4; j >>= 1) {
            #pragma unroll
            for (int p = 0; p < 2; p++) {
                int r = lane + p * 64;
                int low = r & (j - 1);
                int high = (r & ~(j - 1)) << 1;
                ce_desc(a, sb + (high | low), j, 1024);
            }
            __builtin_amdgcn_wave_barrier();
        }
        {
            u64 v0 = a[t4], v1 = a[t4 + 1], v2 = a[t4 + 2], v3 = a[t4 + 3];
            const bool d = ((t4 & 1024) == 0);
            ceg(v0, v2, d); ceg(v1, v3, d);
            ceg(v0, v1, d); ceg(v2, v3, d);
            a[t4] = v0; a[t4 + 1] = v1; a[t4 + 2] = v2; a[t4 + 3] = v3;
        }
    }
    __syncthreads();
}

// exact reference-order IoU > 0.5 test (byte-identical to passing rounds 3-13)
__device__ __forceinline__ bool iou_gt_half(float4 a, float aa, float4 b, float ab) {
    float ltx = fmaxf(a.x, b.x);
    float lty = fmaxf(a.y, b.y);
    float rbx = fminf(a.z, b.z);
    float rby = fminf(a.w, b.w);
    float wd = fmaxf(__fsub_rn(rbx, ltx), 0.0f);
    float hd = fmaxf(__fsub_rn(rby, lty), 0.0f);
    float inter = __fmul_rn(wd, hd);
    float uni = __fsub_rn(__fadd_rn(aa, ab), inter);
    float m = fmaxf(uni, 1e-8f);
    float d2 = __fmul_rn(2.0f, inter);
    bool sup = d2 > m;
    if (sup && (__fsub_rn(d2, m) <= __fmul_rn(m, 1.2e-7f)))
        sup = __fdiv_rn(inter, m) > IOU_T;
    return sup;
}

__device__ __forceinline__ float bcast(float v, int sl) {
    return __int_as_float(__builtin_amdgcn_readlane(__float_as_int(v), sl));
}

// bulk-gather boxes+areas of the first 512 sorted candidates into LDS (512 thr)
__device__ __forceinline__ void prefetch512(const u64* cand, const float* xb,
        float4* pbox, float* parea, int tid) {
    u64 k = cand[tid];
    u32 orig = 2047u - (u32)(k & 0x7FFu);
    float4 bx = *(const float4*)(xb + (size_t)orig * ROW);
    pbox[tid] = bx;
    parea[tid] = __fmul_rn(__fsub_rn(bx.z, bx.x), __fsub_rn(bx.w, bx.y));
    __syncthreads();
}

// wave-aggregated compaction push: 1 LDS atomic per wave instead of 64.
// Placement order differs from the serial-atomic version but the selected
// key SET is identical and the bitonic sort output is placement-independent
// (keys are unique), so downstream results are bit-identical.
__device__ __forceinline__ void push_sel(u64* comp, u32* s_cnt, bool pred,
                                         u64 key, int lane) {
    u64 bal = __ballot(pred);
    u32 base = 0;
    if (lane == 0 && bal) base = atomicAdd(s_cnt, (u32)__popcll(bal));
    base = (u32)__shfl((int)base, 0, 64);
    if (pred) {
        u32 off = (u32)__popcll(bal & ((1ULL << lane) - 1ULL));
        comp[base + off] = key;
    }
}

// Chunked greedy, 8-wave version. Waves 0+4 build the in-chunk suppression
// column mask (halves each, OR'd via LDS); waves 1-3,5-7 test vs previously
// kept boxes (6-way split). Serial sweep on wave 0, stores deferred.
// IoU calls use identical operand order as the verified serial path.
__device__ __forceinline__ int greedy(const u64* cand, int maxch, const float* xb,
        const float4* pbox, const float* parea,
        float4* s_cbox, float* s_car, u64* s_cmhi,
        float4* kept_box, float* kept_area, u64* kept_key,
        u64* s_sup, int* s_kept, int* s_done, int tid, int lane, int wv,
        int keptc_in) {
    if (tid == 0) { *s_kept = keptc_in; *s_done = 0; }
    __syncthreads();
    int keptc = keptc_in;
    for (int ch = 0; ch < maxch; ch++) {
        int n = ch * 64 + lane;
        u64 mykey = cand[n];
        float sc = __uint_as_float((u32)(mykey >> 32));
        bool valid = sc > SCORE_T;
        u64 vball = __ballot(valid);
        if (vball == 0ULL) break;

        float4 bx; float ar;
        const float4* cb; const float* ca;
        if (ch < 8) {
            bx = pbox[n];
            ar = parea[n];
            cb = pbox + ch * 64;
            ca = parea + ch * 64;
        } else {
            u32 orig = 2047u - (u32)(mykey & 0x7FFu);
            bx = *(const float4*)(xb + (size_t)orig * ROW);
            ar = __fmul_rn(__fsub_rn(bx.z, bx.x), __fsub_rn(bx.w, bx.y));
            // waves 0 and 4 each write ALL 64 slots (identical values), so
            // each reads only its own wave's writes -> wave_barrier suffices
            if (wv == 0 || wv == 4) { s_cbox[lane] = bx; s_car[lane] = ar; }
            __builtin_amdgcn_wave_barrier();
            cb = s_cbox; ca = s_car;
        }

        u64 cm_lo = 0ULL;
        if (wv == 0 || wv == 4) {
            u64 colmask = 0ULL;
            const int j0 = (wv == 0) ? 0 : 32;
            #pragma unroll 4
            for (int jj = 0; jj < 32; jj++) {
                int j = j0 + jj;
                bool s = iou_gt_half(bx, ar, cb[j], ca[j]);
                colmask |= ((u64)s) << j;
            }
            if (wv == 4) s_cmhi[lane] = colmask; else cm_lo = colmask;
        } else {
            int widx = (wv < 4) ? (wv - 1) : (wv - 2);   // 0..5
            bool supA = false;
            int t = widx;
            for (; t + 18 < keptc; t += 24) {
                float4 kb0 = kept_box[t],      kb1 = kept_box[t + 6];
                float4 kb2 = kept_box[t + 12], kb3 = kept_box[t + 18];
                float ka0 = kept_area[t],      ka1 = kept_area[t + 6];
                float ka2 = kept_area[t + 12], ka3 = kept_area[t + 18];
                bool s0 = iou_gt_half(bx, ar, kb0, ka0);
                bool s1 = iou_gt_half(bx, ar, kb1, ka1);
                bool s2 = iou_gt_half(bx, ar, kb2, ka2);
                bool s3 = iou_gt_half(bx, ar, kb3, ka3);
                supA = supA | ((s0 | s1) | (s2 | s3));
            }
            for (; t < keptc; t += 6)
                supA = supA | iou_gt_half(bx, ar, kept_box[t], kept_area[t]);
            u64 supm = __ballot(supA);
            if (lane == 0) s_sup[wv] = supm;
        }
        __syncthreads();                   // B1

        if (wv == 0) {
            u64 colmask = cm_lo | s_cmhi[lane];
            u64 alive = vball & ~s_sup[1] & ~s_sup[2] & ~s_sup[3]
                              & ~s_sup[5] & ~s_sup[6] & ~s_sup[7];
            int kept = keptc;
            u64 keptbits = 0ULL;
            int donef = 0;
            while (alive) {
                int bsel = (int)__builtin_ctzll(alive);
                keptbits |= 1ULL << bsel;
                kept++;
                if (kept >= OUT_K) { donef = 1; break; }
                alive &= alive - 1;
                if (!alive) break;
                alive &= ~__ballot(((colmask >> bsel) & 1ULL) != 0ULL);
            }
            // deferred parallel store; selection order == ascending lane order
            u32 rank = (u32)__popcll(keptbits & ((1ULL << lane) - 1ULL));
            if ((keptbits >> lane) & 1ULL) {
                int idx = keptc + (int)rank;
                kept_key[idx] = mykey;
                kept_box[idx] = bx;
                kept_area[idx] = ar;
            }
            if (lane == 0) { *s_kept = kept; if (donef) *s_done = 1; }
        }
        __syncthreads();                   // B2
        keptc = *s_kept;
        if (*s_done) break;
        if (__popcll(vball) < 64) break;
    }
    __syncthreads();
    return keptc;
}

// ---- Kernel T: coalesced transpose of scores into [B][C][N] ----
__global__ __launch_bounds__(256) void transpose_kernel(
        const float* __restrict__ x, float* __restrict__ st) {
    const int t = blockIdx.x;
    const int b = t >> 5;
    const int rb = t & 31;
    const int tid = threadIdx.x;
    __shared__ float lds[64 * 85];

    const float* src = x + ((size_t)b * NN + (size_t)rb * 64) * ROW;
    #pragma unroll
    for (int q = 0; q < 6; q++) {
        int i4 = q * 256 + tid;
        if (i4 < 1344) {
            float4 v = *(const float4*)(src + (size_t)i4 * 4);
            int r = i4 / 21;
            int kq = (i4 % 21) * 4;
            float* d = lds + r * 85 + kq;
            d[0] = v.x; d[1] = v.y; d[2] = v.z; d[3] = v.w;
        }
    }
    __syncthreads();
    const int n0 = rb * 64;
    #pragma unroll
    for (int q = 0; q < 20; q++) {
        int j = q * 256 + tid;
        int c = j >> 6;
        int r = j & 63;
        st[(size_t)(b * NC + c) * NN + n0 + r] = lds[r * 85 + 4 + c];
    }
}

// ---- Kernel A: 512 threads. histogram-select -> sort1024 -> prefetch -> greedy
__global__ __launch_bounds__(512) void nms_kernel(
        const float* __restrict__ x, const float* __restrict__ scores_t,
        u64* __restrict__ cand_key) {
    const int bc = blockIdx.x;
    const int b = bc / NC;
    const int c = bc % NC;
    const int tid = threadIdx.x;
    const int lane = tid & 63;
    const int wv = tid >> 6;        // 0..7

    __shared__ __align__(16) u64 arr[2048];
    u64* comp = arr;
    u32* hist = (u32*)(arr + 1024);
    __shared__ __align__(16) float4 s_pbox[512];
    __shared__ float s_parea[512];
    __shared__ __align__(16) float4 s_cbox[64];
    __shared__ float s_car[64];
    __shared__ u64 s_cmhi[64];
    __shared__ float4 kept_box[OUT_K];
    __shared__ float kept_area[OUT_K];
    __shared__ u64 kept_key[OUT_K];
    __shared__ u64 s_sup[8];
    __shared__ u32 s_wsum[4];
    __shared__ u32 s_cnt, s_m;
    __shared__ int s_kept, s_done, s_thr;

    const float* xb = x + (size_t)b * NN * ROW;
    const float* sct = scores_t + (size_t)(b * NC + c) * NN;

    if (tid < 256) hist[tid] = 0;
    __syncthreads();
    float scv[4];
    #pragma unroll
    for (int w = 0; w < 4; w++) {
        int n = w * 512 + tid;
        float sc = sct[n];
        scv[w] = sc;
        int bin = (int)(sc * 256.0f); bin = bin > 255 ? 255 : bin;
        atomicAdd(&hist[bin], 1u);
    }
    __syncthreads();

    u32 cnt_mine = 0, incl = 0, suf = 0;
    if (tid < 256) {
        cnt_mine = hist[tid];
        incl = cnt_mine;
        #pragma unroll
        for (int off = 1; off < 64; off <<= 1) {
            u32 v = __shfl_down(incl, off, 64);
            if (lane + off < 64) incl += v;
        }
        if (lane == 0) s_wsum[wv] = incl;
    }
    __syncthreads();
    if (tid < 256) {
        u32 above = 0;
        #pragma unroll
        for (int w = 0; w < 4; w++) above += (w > wv) ? s_wsum[w] : 0;
        suf = incl + above;
    }

    if (tid == 0) s_thr = 2;
    __syncthreads();
    if (tid < 256 && suf >= TGT && suf - cnt_mine < TGT) s_thr = tid;
    __syncthreads();
    int t1 = s_thr;
    if (tid == t1) s_m = suf;
    __syncthreads();
    u32 m_tot = s_m;

    bool fb = (m_tot > POOL);
    int kept = 0;
    if (!fb) {
        if (tid == 0) s_cnt = 0;
        __syncthreads();
        #pragma unroll
        for (int w = 0; w < 4; w++) {
            float sc = scv[w];
            int bin = (int)(sc * 256.0f); bin = bin > 255 ? 255 : bin;
            int n = w * 512 + tid;
            u64 key = ((u64)__float_as_uint(sc) << 32) | (u64)(2047 - n);
            push_sel(comp, &s_cnt, bin >= t1, key, lane);
        }
        __syncthreads();
        for (int i = tid; i < POOL; i += 512) if (i >= (int)m_tot) comp[i] = 0ULL;
        __syncthreads();
        sort1024(comp, tid, lane, wv);
        prefetch512(comp, xb, s_pbox, s_parea, tid);
        kept = greedy(comp, POOL / 64, xb, s_pbox, s_parea, s_cbox, s_car, s_cmhi,
                      kept_box, kept_area, kept_key,
                      s_sup, &s_kept, &s_done, tid, lane, wv, 0);

        while (kept < OUT_K && t1 > 2) {
            u32 T2 = m_tot + TGT;
            if (tid == 0) s_thr = 2;
            __syncthreads();
            if (tid < 256 && suf >= T2 && suf - cnt_mine < T2) s_thr = tid;
            __syncthreads();
            int t2 = s_thr;
            if (tid == t2) s_m = suf;
            __syncthreads();
            u32 m2 = s_m;
            u32 size = m2 - m_tot;
            if (size == 0) break;
            if (size > POOL) { fb = true; break; }
            if (tid == 0) s_cnt = 0;
            __syncthreads();
            #pragma unroll
            for (int w = 0; w < 4; w++) {
                float sc = scv[w];
                int bin = (int)(sc * 256.0f); bin = bin > 255 ? 255 : bin;
                int n = w * 512 + tid;
                u64 key = ((u64)__float_as_uint(sc) << 32) | (u64)(2047 - n);
                push_sel(comp, &s_cnt, bin >= t2 && bin < t1, key, lane);
            }
            __syncthreads();
            for (int i = tid; i < POOL; i += 512) if (i >= (int)size) comp[i] = 0ULL;
            __syncthreads();
            sort1024(comp, tid, lane, wv);
            prefetch512(comp, xb, s_pbox, s_parea, tid);
            kept = greedy(comp, POOL / 64, xb, s_pbox, s_parea, s_cbox, s_car, s_cmhi,
                          kept_box, kept_area, kept_key,
                          s_sup, &s_kept, &s_done, tid, lane, wv, kept);
            m_tot = m2; t1 = t2;
        }
    }
    if (fb) {
        __syncthreads();
        #pragma unroll
        for (int w = 0; w < 4; w++) {
            int n = w * 512 + tid;
            arr[n] = ((u64)__float_as_uint(scv[w]) << 32) | (u64)(2047 - n);
        }
        __syncthreads();
        sort2048(arr, tid, lane, wv);
        prefetch512(arr, xb, s_pbox, s_parea, tid);
        kept = greedy(arr, 32, xb, s_pbox, s_parea, s_cbox, s_car, s_cmhi,
                      kept_box, kept_area, kept_key,
                      s_sup, &s_kept, &s_done, tid, lane, wv, 0);
    }

    const int base_o = bc * OUT_K;
    if (tid < OUT_K) {
        u64 ok = 0ULL;
        if (tid < kept) {
            u64 kk = kept_key[tid];
            u32 flat = (u32)(c * OUT_K + tid);
            u32 orig = 2047u - (u32)(kk & 0x7FFu);
            ok = (kk & 0xFFFFFFFF00000000ULL) |
                 ((u64)(0x3FFFu - flat) << 11) | (u64)orig;
        }
        cand_key[base_o + tid] = ok;
    }
}

// ---- Kernel B1: 80 blocks x 256 threads. Each block tree-merges its 8 runs
//      of 200 and writes top-256 in place into its block-owned region. ----
__global__ __launch_bounds__(256) void merge8_kernel(u64* __restrict__ cand_key) {
    const int blk = blockIdx.x;          // 0..79
    const int b = blk / 10;
    const int g = blk % 10;
    const int tid = threadIdx.x;
    const int lane = tid & 63;
    const int wv = tid >> 6;
    __shared__ __align__(16) u64 seg[2048];

    u64* src = cand_key + (size_t)(b * NC + g * 8) * OUT_K;

    #pragma unroll
    for (int q = 0; q < 8; q++) {
        seg[q * 256 + tid] = (tid < OUT_K) ? src[q * OUT_K + tid] : 0ULL;
    }
    __syncthreads();
    pair_merge256(seg, wv * 512, 256, lane);
    __syncthreads();
    if (wv < 2) pair_merge256(seg, wv * 1024, 512, lane);
    __syncthreads();
    if (wv == 0) pair_merge256(seg, 0, 1024, lane);
    __syncthreads();
    src[tid] = seg[tid];
}

// ---- Kernel B2: 8 blocks x 256 threads. Merge the batch's 10 surviving
//      256-runs (depth-4 tree), decode top-200. ----
__global__ __launch_bounds__(256) void final_kernel(
        const float* __restrict__ x, const u64* __restrict__ cand_key,
        float* __restrict__ out) {
    const int b = blockIdx.x;
    const int tid = threadIdx.x;
    const int lane = tid & 63;
    const int wv = tid >> 6;
    __shared__ __align__(16) u64 seg[2560];

    #pragma unroll
    for (int q = 0; q < 10; q++) {
        seg[q * 256 + tid] = cand_key[(size_t)(b * NC + q * 8) * OUT_K + tid];
    }
    __syncthreads();
    pair_merge256(seg, wv * 512, 256, lane);
    __syncthreads();
    if (wv == 0) pair_merge256(seg, 0, 512, lane);
    else if (wv == 1) pair_merge256(seg, 1024, 512, lane);
    else if (wv == 2) pair_merge256(seg, 2048, 256, lane);
    __syncthreads();
    if (wv == 0) pair_merge256(seg, 0, 1024, lane);
    __syncthreads();
    if (wv == 0) pair_merge256(seg, 0, 2048, lane);
    __syncthreads();

    const float* xb = x + (size_t)b * NN * ROW;
    if (tid < OUT_K) {
        u64 kk = seg[tid];
        float* o = out + ((size_t)b * OUT_K + tid) * 6;
        if (kk == 0ULL) {
            o[0] = 0.f; o[1] = 0.f; o[2] = 0.f; o[3] = 0.f; o[4] = 0.f; o[5] = 0.f;
        } else {
            u32 lo = (u32)(kk & 0xFFFFFFFFu);
            u32 flat = 0x3FFFu - ((lo >> 11) & 0x3FFFu);
            int cls = flat / OUT_K;
            u32 n = lo & 0x7FFu;
            float scf = __uint_as_float((u32)(kk >> 32));
            float4 bx = *(const float4*)(xb + (size_t)n * ROW);
            o[0] = (float)cls;
            o[1] = scf;
            o[2] = fminf(fmaxf(bx.x, 0.0f), 1.0f);
            o[3] = fminf(fmaxf(bx.y, 0.0f), 1.0f);
            o[4] = fminf(fmaxf(bx.z, 0.0f), 1.0f);
            o[5] = fminf(fmaxf(bx.w, 0.0f), 1.0f);
        }
    }
}

extern "C" void kernel_launch(void* const* d_in, const int* in_sizes, int n_in,
                              void* d_out, int out_size, void* d_ws, size_t ws_size,
                              hipStream_t stream) {
    const float* x = (const float*)d_in[0];
    float* out = (float*)d_out;
    u64* cand_key = (u64*)d_ws;                            // 1,024,000 B
    float* scores_t = (float*)((char*)d_ws + 1024 * 1024); // 5,242,880 B
    transpose_kernel<<<NB * 32, 256, 0, stream>>>(x, scores_t);
    nms_kernel<<<NB * NC, 512, 0, stream>>>(x, scores_t, cand_key);
    merge8_kernel<<<NB * 10, 256, 0, stream>>>(cand_key);
    final_kernel<<<NB, 256, 0, stream>>>(x, cand_key, out);
}

// Round 5
// 133.052 us; speedup vs baseline: 1.7952x; 1.7952x over previous
//
#include <hip/hip_runtime.h>
#include <stdint.h>

typedef unsigned long long u64;
typedef unsigned int u32;

#define NB 8
#define NN 2048
#define NC 80
#define ROW 84
#define OUT_K 200
#define IOU_T 0.5f
#define SCORE_T 0.01f
#define TGT 896
#define POOL 1024

// ---- compare-exchange, descending network, direction from global index ----
__device__ __forceinline__ void ce_desc(u64* a, int i, int j, int k) {
    u64 a0 = a[i], a1 = a[i + j];
    bool up = ((i & k) == 0);
    if (up ? (a0 < a1) : (a0 > a1)) { a[i] = a1; a[i + j] = a0; }
}

// register compare-exchange; up=true -> larger first (descending pair)
__device__ __forceinline__ void ceg(u64& x, u64& y, bool up) {
    u64 a0 = x, a1 = y;
    if (up ? (a0 < a1) : (a0 > a1)) { x = a1; y = a0; }
}

// wave-local rounds on a 512-elem segment (4 CE/lane/round), j<=256
__device__ __forceinline__ void wave_rounds512(u64* a, int base, int k, int jhi, int lane) {
    for (int j = jhi; j > 0; j >>= 1) {
        #pragma unroll
        for (int p = 0; p < 4; p++) {
            int r = lane + p * 64;
            int low = r & (j - 1);
            int high = (r & ~(j - 1)) << 1;
            ce_desc(a, base + (high | low), j, k);
        }
        __builtin_amdgcn_wave_barrier();
    }
}

// wave-local rounds on a 256-elem segment; k=0x40000000 -> all-descending merge
__device__ __forceinline__ void wave_rounds256(u64* a, int base, int k, int jhi, int lane) {
    for (int j = jhi; j > 0; j >>= 1) {
        #pragma unroll
        for (int p = 0; p < 2; p++) {
            int r = lane + p * 64;
            int low = r & (j - 1);
            int high = (r & ~(j - 1)) << 1;
            ce_desc(a, base + (high | low), j, k);
        }
        __builtin_amdgcn_wave_barrier();
    }
}

// max-combine two desc-sorted 256-runs (base, base+off) -> top-256 sorted desc
__device__ __forceinline__ void pair_merge256(u64* a, int base, int off, int lane) {
    #pragma unroll
    for (int p0 = 0; p0 < 4; p0++) {
        int p = lane + p0 * 64;
        u64 xv = a[base + p];
        u64 yv = a[base + off + 255 - p];
        a[base + p] = xv > yv ? xv : yv;
    }
    __builtin_amdgcn_wave_barrier();
    wave_rounds256(a, base, 0x40000000, 128, lane);
}

// full hybrid bitonic sort of 2048 (desc) — identical network to rounds 4-12
__device__ __forceinline__ void sort2048(u64* key, int tid, int lane, int wv) {
    const int base = wv * 512;
    for (int k = 2; k <= 512; k <<= 1)
        wave_rounds512(key, base, k, k >> 1, lane);
    __syncthreads();
    #pragma unroll
    for (int p = 0; p < 4; p++) {
        int r = tid + p * 256;
        int low = r & 511, high = (r & ~511) << 1;
        ce_desc(key, high | low, 512, 1024);
    }
    __syncthreads();
    wave_rounds512(key, base, 1024, 256, lane);
    __syncthreads();
    #pragma unroll
    for (int p = 0; p < 4; p++) {
        int r = tid + p * 256;
        int low = r & 1023, high = (r & ~1023) << 1;
        ce_desc(key, high | low, 1024, 2048);
    }
    __syncthreads();
    #pragma unroll
    for (int p = 0; p < 4; p++) {
        int r = tid + p * 256;
        int low = r & 511, high = (r & ~511) << 1;
        ce_desc(key, high | low, 512, 2048);
    }
    __syncthreads();
    wave_rounds512(key, base, 2048, 256, lane);
    __syncthreads();
}

// bitonic sort of 1024 (desc): 4 elems/thread, register-fused j<=2 rounds
__device__ __forceinline__ void sort1024(u64* a, int tid, int lane, int wv) {
    const int t4 = tid * 4;
    const int sb = wv * 256;
    {
        u64 v0 = a[t4], v1 = a[t4 + 1], v2 = a[t4 + 2], v3 = a[t4 + 3];
        ceg(v0, v1, true);
        ceg(v2, v3, false);
        const bool d4 = ((t4 & 4) == 0);
        ceg(v0, v2, d4); ceg(v1, v3, d4);
        ceg(v0, v1, d4); ceg(v2, v3, d4);
        a[t4] = v0; a[t4 + 1] = v1; a[t4 + 2] = v2; a[t4 + 3] = v3;
    }
    __builtin_amdgcn_wave_barrier();
    for (int k = 8; k <= 256; k <<= 1) {
        for (int j = k >> 1; j >= 4; j >>= 1) {
            #pragma unroll
            for (int p = 0; p < 2; p++) {
                int r = lane + p * 64;
                int low = r & (j - 1);
                int high = (r & ~(j - 1)) << 1;
                ce_desc(a, sb + (high | low), j, k);
            }
            __builtin_amdgcn_wave_barrier();
        }
        {
            u64 v0 = a[t4], v1 = a[t4 + 1], v2 = a[t4 + 2], v3 = a[t4 + 3];
            const bool d = ((t4 & k) == 0);
            ceg(v0, v2, d); ceg(v1, v3, d);
            ceg(v0, v1, d); ceg(v2, v3, d);
            a[t4] = v0; a[t4 + 1] = v1; a[t4 + 2] = v2; a[t4 + 3] = v3;
        }
        __builtin_amdgcn_wave_barrier();
    }
    __syncthreads();
    #pragma unroll
    for (int p = 0; p < 2; p++) {
        int r = tid + p * 256;
        int low = r & 255, high = (r & ~255) << 1;
        ce_desc(a, high | low, 256, 512);
    }
    __syncthreads();
    for (int j = 128; j >= 4; j >>= 1) {
        #pragma unroll
        for (int p = 0; p < 2; p++) {
            int r = lane + p * 64;
            int low = r & (j - 1);
            int high = (r & ~(j - 1)) << 1;
            ce_desc(a, sb + (high | low), j, 512);
        }
        __builtin_amdgcn_wave_barrier();
    }
    {
        u64 v0 = a[t4], v1 = a[t4 + 1], v2 = a[t4 + 2], v3 = a[t4 + 3];
        const bool d = ((t4 & 512) == 0);
        ceg(v0, v2, d); ceg(v1, v3, d);
        ceg(v0, v1, d); ceg(v2, v3, d);
        a[t4] = v0; a[t4 + 1] = v1; a[t4 + 2] = v2; a[t4 + 3] = v3;
    }
    __syncthreads();
    #pragma unroll
    for (int p = 0; p < 2; p++) {
        int r = tid + p * 256;
        int low = r & 511, high = (r & ~511) << 1;
        ce_desc(a, high | low, 512, 1024);
    }
    __syncthreads();
    #pragma unroll
    for (int p = 0; p < 2; p++) {
        int r = tid + p * 256;
        int low = r & 255, high = (r & ~255) << 1;
        ce_desc(a, high | low, 256, 1024);
    }
    __syncthreads();
    for (int j = 128; j >= 4; j >>= 1) {
        #pragma unroll
        for (int p = 0; p < 2; p++) {
            int r = lane + p * 64;
            int low = r & (j - 1);
            int high = (r & ~(j - 1)) << 1;
            ce_desc(a, sb + (high | low), j, 1024);
        }
        __builtin_amdgcn_wave_barrier();
    }
    {
        u64 v0 = a[t4], v1 = a[t4 + 1], v2 = a[t4 + 2], v3 = a[t4 + 3];
        const bool d = ((t4 & 1024) == 0);
        ceg(v0, v2, d); ceg(v1, v3, d);
        ceg(v0, v1, d); ceg(v2, v3, d);
        a[t4] = v0; a[t4 + 1] = v1; a[t4 + 2] = v2; a[t4 + 3] = v3;
    }
    __syncthreads();
}

// exact reference-order IoU > 0.5 test (byte-identical to passing rounds 3-13)
__device__ __forceinline__ bool iou_gt_half(float4 a, float aa, float4 b, float ab) {
    float ltx = fmaxf(a.x, b.x);
    float lty = fmaxf(a.y, b.y);
    float rbx = fminf(a.z, b.z);
    float rby = fminf(a.w, b.w);
    float wd = fmaxf(__fsub_rn(rbx, ltx), 0.0f);
    float hd = fmaxf(__fsub_rn(rby, lty), 0.0f);
    float inter = __fmul_rn(wd, hd);
    float uni = __fsub_rn(__fadd_rn(aa, ab), inter);
    float m = fmaxf(uni, 1e-8f);
    float d2 = __fmul_rn(2.0f, inter);
    bool sup = d2 > m;
    if (sup && (__fsub_rn(d2, m) <= __fmul_rn(m, 1.2e-7f)))
        sup = __fdiv_rn(inter, m) > IOU_T;
    return sup;
}

// bulk-gather boxes+areas of the first 1024 sorted candidates into LDS.
// Area computed with the exact same float ops as the greedy inline path.
__device__ __forceinline__ void prefetch1024(const u64* cand, const float* xb,
        float4* pbox, float* parea, int tid) {
    #pragma unroll
    for (int r = 0; r < 4; r++) {
        int i = r * 256 + tid;
        u64 k = cand[i];
        u32 orig = 2047u - (u32)(k & 0x7FFu);
        float4 bx = *(const float4*)(xb + (size_t)orig * ROW);
        pbox[i] = bx;
        parea[i] = __fmul_rn(__fsub_rn(bx.z, bx.x), __fsub_rn(bx.w, bx.y));
    }
    __syncthreads();
}

// Chunked greedy over a desc-sorted array (low 11 bits = 2047-n).
// Per chunk, ALL 4 waves each compute (a) a 16-bit quarter of the in-chunk
// suppression column mask (bit j = chunk candidate j suppresses me) and
// (b) a stride-4 share of the tests vs previously-kept boxes (R12-verbatim
// stride pattern). Serial sweep on wave 0 is pure mask algebra, stores
// deferred. IoU calls use identical operand order as the verified path;
// OR-reduction over identical test sets -> bit-identical decisions.
__device__ __forceinline__ int greedy(const u64* cand, int maxch, const float* xb,
        const float4* pbox, const float* parea,
        float4* s_cbox, float* s_car, u64* s_cm,
        float4* kept_box, float* kept_area, u64* kept_key,
        u64* s_sup, int* s_kept, int* s_done, int tid, int lane, int wv,
        int keptc_in) {
    if (tid == 0) { *s_kept = keptc_in; *s_done = 0; }
    __syncthreads();
    int keptc = keptc_in;
    for (int ch = 0; ch < maxch; ch++) {
        int n = ch * 64 + lane;
        u64 mykey = cand[n];
        float sc = __uint_as_float((u32)(mykey >> 32));
        bool valid = sc > SCORE_T;
        u64 vball = __ballot(valid);
        if (vball == 0ULL) break;

        float4 bx; float ar;
        const float4* cb; const float* ca;
        if (ch < 16) {
            bx = pbox[n];
            ar = parea[n];
            cb = pbox + ch * 64;
            ca = parea + ch * 64;
        } else {
            // fb path beyond the prefetched pool: stage chunk boxes for all
            // waves (each wave consumes them for its colmask quarter)
            u32 orig = 2047u - (u32)(mykey & 0x7FFu);
            bx = *(const float4*)(xb + (size_t)orig * ROW);
            ar = __fmul_rn(__fsub_rn(bx.z, bx.x), __fsub_rn(bx.w, bx.y));
            if (wv == 0) { s_cbox[lane] = bx; s_car[lane] = ar; }
            __syncthreads();
            cb = s_cbox; ca = s_car;
        }

        // (a) colmask quarter: j in [wv*16, wv*16+16)
        u64 cm = 0ULL;
        {
            const int j0 = wv * 16;
            #pragma unroll 4
            for (int jj = 0; jj < 16; jj++) {
                int j = j0 + jj;
                bool s = iou_gt_half(bx, ar, cb[j], ca[j]);
                cm |= ((u64)s) << j;
            }
            s_cm[wv * 64 + lane] = cm;
        }
        // (b) kept-tests, stride 4 offset wv (R12-verbatim distribution)
        {
            bool supA = false;
            int t = wv;
            for (; t + 12 < keptc; t += 16) {
                float4 kb0 = kept_box[t],     kb1 = kept_box[t + 4];
                float4 kb2 = kept_box[t + 8], kb3 = kept_box[t + 12];
                float ka0 = kept_area[t],     ka1 = kept_area[t + 4];
                float ka2 = kept_area[t + 8], ka3 = kept_area[t + 12];
                bool s0 = iou_gt_half(bx, ar, kb0, ka0);
                bool s1 = iou_gt_half(bx, ar, kb1, ka1);
                bool s2 = iou_gt_half(bx, ar, kb2, ka2);
                bool s3 = iou_gt_half(bx, ar, kb3, ka3);
                supA = supA | ((s0 | s1) | (s2 | s3));
            }
            for (; t < keptc; t += 4)
                supA = supA | iou_gt_half(bx, ar, kept_box[t], kept_area[t]);
            u64 supm = __ballot(supA);
            if (lane == 0) s_sup[wv] = supm;
        }
        __syncthreads();                   // B1

        if (wv == 0) {
            u64 colmask = cm | s_cm[64 + lane] | s_cm[128 + lane] | s_cm[192 + lane];
            u64 alive = vball & ~s_sup[0] & ~s_sup[1] & ~s_sup[2] & ~s_sup[3];
            int kept = keptc;
            u64 keptbits = 0ULL;
            int donef = 0;
            while (alive) {
                int bsel = (int)__builtin_ctzll(alive);
                keptbits |= 1ULL << bsel;
                kept++;
                if (kept >= OUT_K) { donef = 1; break; }
                alive &= alive - 1;
                if (!alive) break;
                alive &= ~__ballot(((colmask >> bsel) & 1ULL) != 0ULL);
            }
            // deferred parallel store; selection order == ascending lane order
            u32 rank = (u32)__popcll(keptbits & ((1ULL << lane) - 1ULL));
            if ((keptbits >> lane) & 1ULL) {
                int idx = keptc + (int)rank;
                kept_key[idx] = mykey;
                kept_box[idx] = bx;
                kept_area[idx] = ar;
            }
            if (lane == 0) { *s_kept = kept; if (donef) *s_done = 1; }
        }
        __syncthreads();                   // B2
        keptc = *s_kept;
        if (*s_done) break;
        if (__popcll(vball) < 64) break;
    }
    __syncthreads();
    return keptc;
}

// ---- Kernel T: coalesced transpose of scores into [B][C][N] ----
// 256 blocks x 256 threads; each block stages 64 rows (84 floats) in LDS
// (row stride 85: gcd(21,32)=1 -> conflict-free col reads)
__global__ __launch_bounds__(256) void transpose_kernel(
        const float* __restrict__ x, float* __restrict__ st) {
    const int t = blockIdx.x;
    const int b = t >> 5;
    const int rb = t & 31;
    const int tid = threadIdx.x;
    __shared__ float lds[64 * 85];

    const float* src = x + ((size_t)b * NN + (size_t)rb * 64) * ROW;
    #pragma unroll
    for (int q = 0; q < 6; q++) {
        int i4 = q * 256 + tid;
        if (i4 < 1344) {
            float4 v = *(const float4*)(src + (size_t)i4 * 4);
            int r = i4 / 21;
            int kq = (i4 % 21) * 4;
            float* d = lds + r * 85 + kq;
            d[0] = v.x; d[1] = v.y; d[2] = v.z; d[3] = v.w;
        }
    }
    __syncthreads();
    const int n0 = rb * 64;
    #pragma unroll
    for (int q = 0; q < 20; q++) {
        int j = q * 256 + tid;
        int c = j >> 6;
        int r = j & 63;
        st[(size_t)(b * NC + c) * NN + n0 + r] = lds[r * 85 + 4 + c];
    }
}

// ---- Kernel A: histogram-select -> sort1024 -> prefetch -> greedy ----
__global__ __launch_bounds__(256) void nms_kernel(
        const float* __restrict__ x, const float* __restrict__ scores_t,
        u64* __restrict__ cand_key) {
    const int bc = blockIdx.x;
    const int b = bc / NC;
    const int c = bc % NC;
    const int tid = threadIdx.x;
    const int lane = tid & 63;
    const int wv = tid >> 6;

    __shared__ __align__(16) u64 arr[2048];
    u64* comp = arr;
    u32* hist = (u32*)(arr + 1024);
    __shared__ __align__(16) float4 s_pbox[1024];
    __shared__ float s_parea[1024];
    __shared__ __align__(16) float4 s_cbox[64];
    __shared__ float s_car[64];
    __shared__ u64 s_cm[256];
    __shared__ float4 kept_box[OUT_K];
    __shared__ float kept_area[OUT_K];
    __shared__ u64 kept_key[OUT_K];
    __shared__ u64 s_sup[4];
    __shared__ u32 s_wsum[4];
    __shared__ u32 s_cnt, s_m;
    __shared__ int s_kept, s_done, s_thr;

    const float* xb = x + (size_t)b * NN * ROW;
    const float* sct = scores_t + (size_t)(b * NC + c) * NN;

    hist[tid] = 0;
    __syncthreads();
    float scv[8];
    #pragma unroll
    for (int w = 0; w < 8; w++) {
        int n = w * 256 + tid;
        float sc = sct[n];
        scv[w] = sc;
        int bin = (int)(sc * 256.0f); bin = bin > 255 ? 255 : bin;
        atomicAdd(&hist[bin], 1u);
    }
    __syncthreads();

    u32 cnt_mine = hist[tid];
    u32 incl = cnt_mine;
    #pragma unroll
    for (int off = 1; off < 64; off <<= 1) {
        u32 v = __shfl_down(incl, off, 64);
        if (lane + off < 64) incl += v;
    }
    if (lane == 0) s_wsum[wv] = incl;
    __syncthreads();
    u32 above = 0;
    #pragma unroll
    for (int w = 0; w < 4; w++) above += (w > wv) ? s_wsum[w] : 0;
    const u32 suf = incl + above;

    if (tid == 0) s_thr = 2;
    __syncthreads();
    if (suf >= TGT && suf - cnt_mine < TGT) s_thr = tid;
    __syncthreads();
    int t1 = s_thr;
    if (tid == t1) s_m = suf;
    __syncthreads();
    u32 m_tot = s_m;

    bool fb = (m_tot > POOL);
    int kept = 0;
    if (!fb) {
        if (tid == 0) s_cnt = 0;
        __syncthreads();
        #pragma unroll
        for (int w = 0; w < 8; w++) {
            float sc = scv[w];
            int bin = (int)(sc * 256.0f); bin = bin > 255 ? 255 : bin;
            if (bin >= t1) {
                int n = w * 256 + tid;
                u32 p = atomicAdd(&s_cnt, 1u);
                comp[p] = ((u64)__float_as_uint(sc) << 32) | (u64)(2047 - n);
            }
        }
        __syncthreads();
        for (int i = tid; i < POOL; i += 256) if (i >= (int)m_tot) comp[i] = 0ULL;
        __syncthreads();
        sort1024(comp, tid, lane, wv);
        prefetch1024(comp, xb, s_pbox, s_parea, tid);
        kept = greedy(comp, POOL / 64, xb, s_pbox, s_parea, s_cbox, s_car, s_cm,
                      kept_box, kept_area, kept_key,
                      s_sup, &s_kept, &s_done, tid, lane, wv, 0);

        while (kept < OUT_K && t1 > 2) {
            u32 T2 = m_tot + TGT;
            if (tid == 0) s_thr = 2;
            __syncthreads();
            if (suf >= T2 && suf - cnt_mine < T2) s_thr = tid;
            __syncthreads();
            int t2 = s_thr;
            if (tid == t2) s_m = suf;
            __syncthreads();
            u32 m2 = s_m;
            u32 size = m2 - m_tot;
            if (size == 0) break;
            if (size > POOL) { fb = true; break; }
            if (tid == 0) s_cnt = 0;
            __syncthreads();
            #pragma unroll
            for (int w = 0; w < 8; w++) {
                float sc = scv[w];
                int bin = (int)(sc * 256.0f); bin = bin > 255 ? 255 : bin;
                if (bin >= t2 && bin < t1) {
                    int n = w * 256 + tid;
                    u32 p = atomicAdd(&s_cnt, 1u);
                    comp[p] = ((u64)__float_as_uint(sc) << 32) | (u64)(2047 - n);
                }
            }
            __syncthreads();
            for (int i = tid; i < POOL; i += 256) if (i >= (int)size) comp[i] = 0ULL;
            __syncthreads();
            sort1024(comp, tid, lane, wv);
            prefetch1024(comp, xb, s_pbox, s_parea, tid);
            kept = greedy(comp, POOL / 64, xb, s_pbox, s_parea, s_cbox, s_car, s_cm,
                          kept_box, kept_area, kept_key,
                          s_sup, &s_kept, &s_done, tid, lane, wv, kept);
            m_tot = m2; t1 = t2;
        }
    }
    if (fb) {
        __syncthreads();
        #pragma unroll
        for (int w = 0; w < 8; w++) {
            int n = w * 256 + tid;
            arr[n] = ((u64)__float_as_uint(scv[w]) << 32) | (u64)(2047 - n);
        }
        __syncthreads();
        sort2048(arr, tid, lane, wv);
        prefetch1024(arr, xb, s_pbox, s_parea, tid);
        kept = greedy(arr, 32, xb, s_pbox, s_parea, s_cbox, s_car, s_cm,
                      kept_box, kept_area, kept_key,
                      s_sup, &s_kept, &s_done, tid, lane, wv, 0);
    }

    const int base_o = bc * OUT_K;
    if (tid < OUT_K) {
        u64 ok = 0ULL;
        if (tid < kept) {
            u64 kk = kept_key[tid];
            u32 flat = (u32)(c * OUT_K + tid);
            u32 orig = 2047u - (u32)(kk & 0x7FFu);
            ok = (kk & 0xFFFFFFFF00000000ULL) |
                 ((u64)(0x3FFFu - flat) << 11) | (u64)orig;
        }
        cand_key[base_o + tid] = ok;
    }
}

// ---- Kernel B1: 80 blocks x 256 threads. Each block tree-merges its 8 runs
//      of 200 and writes top-256 in place into its block-owned region. ----
__global__ __launch_bounds__(256) void merge8_kernel(u64* __restrict__ cand_key) {
    const int blk = blockIdx.x;          // 0..79
    const int b = blk / 10;
    const int g = blk % 10;
    const int tid = threadIdx.x;
    const int lane = tid & 63;
    const int wv = tid >> 6;
    __shared__ __align__(16) u64 seg[2048];

    u64* src = cand_key + (size_t)(b * NC + g * 8) * OUT_K;

    #pragma unroll
    for (int q = 0; q < 8; q++) {
        seg[q * 256 + tid] = (tid < OUT_K) ? src[q * OUT_K + tid] : 0ULL;
    }
    __syncthreads();
    pair_merge256(seg, wv * 512, 256, lane);
    __syncthreads();
    if (wv < 2) pair_merge256(seg, wv * 1024, 512, lane);
    __syncthreads();
    if (wv == 0) pair_merge256(seg, 0, 1024, lane);
    __syncthreads();
    src[tid] = seg[tid];
}

// ---- Kernel B2: 8 blocks x 256 threads. Merge the batch's 10 surviving
//      256-runs (depth-4 tree), decode top-200. ----
__global__ __launch_bounds__(256) void final_kernel(
        const float* __restrict__ x, const u64* __restrict__ cand_key,
        float* __restrict__ out) {
    const int b = blockIdx.x;
    const int tid = threadIdx.x;
    const int lane = tid & 63;
    const int wv = tid >> 6;
    __shared__ __align__(16) u64 seg[2560];

    #pragma unroll
    for (int q = 0; q < 10; q++) {
        seg[q * 256 + tid] = cand_key[(size_t)(b * NC + q * 8) * OUT_K + tid];
    }
    __syncthreads();
    pair_merge256(seg, wv * 512, 256, lane);
    __syncthreads();
    if (wv == 0) pair_merge256(seg, 0, 512, lane);
    else if (wv == 1) pair_merge256(seg, 1024, 512, lane);
    else if (wv == 2) pair_merge256(seg, 2048, 256, lane);
    __syncthreads();
    if (wv == 0) pair_merge256(seg, 0, 1024, lane);
    __syncthreads();
    if (wv == 0) pair_merge256(seg, 0, 2048, lane);
    __syncthreads();

    const float* xb = x + (size_t)b * NN * ROW;
    if (tid < OUT_K) {
        u64 kk = seg[tid];
        float* o = out + ((size_t)b * OUT_K + tid) * 6;
        if (kk == 0ULL) {
            o[0] = 0.f; o[1] = 0.f; o[2] = 0.f; o[3] = 0.f; o[4] = 0.f; o[5] = 0.f;
        } else {
            u32 lo = (u32)(kk & 0xFFFFFFFFu);
            u32 flat = 0x3FFFu - ((lo >> 11) & 0x3FFFu);
            int cls = flat / OUT_K;
            u32 n = lo & 0x7FFu;
            float scf = __uint_as_float((u32)(kk >> 32));
            float4 bx = *(const float4*)(xb + (size_t)n * ROW);
            o[0] = (float)cls;
            o[1] = scf;
            o[2] = fminf(fmaxf(bx.x, 0.0f), 1.0f);
            o[3] = fminf(fmaxf(bx.y, 0.0f), 1.0f);
            o[4] = fminf(fmaxf(bx.z, 0.0f), 1.0f);
            o[5] = fminf(fmaxf(bx.w, 0.0f), 1.0f);
        }
    }
}

extern "C" void kernel_launch(void* const* d_in, const int* in_sizes, int n_in,
                              void* d_out, int out_size, void* d_ws, size_t ws_size,
                              hipStream_t stream) {
    const float* x = (const float*)d_in[0];
    float* out = (float*)d_out;
    u64* cand_key = (u64*)d_ws;                            // 1,024,000 B
    float* scores_t = (float*)((char*)d_ws + 1024 * 1024); // 5,242,880 B
    transpose_kernel<<<NB * 32, 256, 0, stream>>>(x, scores_t);
    nms_kernel<<<NB * NC, 256, 0, stream>>>(x, scores_t, cand_key);
    merge8_kernel<<<NB * 10, 256, 0, stream>>>(cand_key);
    final_kernel<<<NB, 256, 0, stream>>>(x, cand_key, out);
}

// Round 6
// 131.503 us; speedup vs baseline: 1.8163x; 1.0118x over previous
//
#include <hip/hip_runtime.h>
#include <stdint.h>

typedef unsigned long long u64;
typedef unsigned int u32;

#define NB 8
#define NN 2048
#define NC 80
#define ROW 84
#define OUT_K 200
#define IOU_T 0.5f
#define SCORE_T 0.01f
#define TGT 896
#define POOL 1024

// ---- compare-exchange, descending network, direction from global index ----
__device__ __forceinline__ void ce_desc(u64* a, int i, int j, int k) {
    u64 a0 = a[i], a1 = a[i + j];
    bool up = ((i & k) == 0);
    if (up ? (a0 < a1) : (a0 > a1)) { a[i] = a1; a[i + j] = a0; }
}

// register compare-exchange; up=true -> larger first (descending pair)
__device__ __forceinline__ void ceg(u64& x, u64& y, bool up) {
    u64 a0 = x, a1 = y;
    if (up ? (a0 < a1) : (a0 > a1)) { x = a1; y = a0; }
}

// wave-local rounds on a 512-elem segment (4 CE/lane/round), j<=256
__device__ __forceinline__ void wave_rounds512(u64* a, int base, int k, int jhi, int lane) {
    for (int j = jhi; j > 0; j >>= 1) {
        #pragma unroll
        for (int p = 0; p < 4; p++) {
            int r = lane + p * 64;
            int low = r & (j - 1);
            int high = (r & ~(j - 1)) << 1;
            ce_desc(a, base + (high | low), j, k);
        }
        __builtin_amdgcn_wave_barrier();
    }
}

// wave-local rounds on a 256-elem segment; k=0x40000000 -> all-descending merge
__device__ __forceinline__ void wave_rounds256(u64* a, int base, int k, int jhi, int lane) {
    for (int j = jhi; j > 0; j >>= 1) {
        #pragma unroll
        for (int p = 0; p < 2; p++) {
            int r = lane + p * 64;
            int low = r & (j - 1);
            int high = (r & ~(j - 1)) << 1;
            ce_desc(a, base + (high | low), j, k);
        }
        __builtin_amdgcn_wave_barrier();
    }
}

// max-combine two desc-sorted 256-runs (base, base+off) -> top-256 sorted desc
__device__ __forceinline__ void pair_merge256(u64* a, int base, int off, int lane) {
    #pragma unroll
    for (int p0 = 0; p0 < 4; p0++) {
        int p = lane + p0 * 64;
        u64 xv = a[base + p];
        u64 yv = a[base + off + 255 - p];
        a[base + p] = xv > yv ? xv : yv;
    }
    __builtin_amdgcn_wave_barrier();
    wave_rounds256(a, base, 0x40000000, 128, lane);
}

// full hybrid bitonic sort of 2048 (desc) — identical network to rounds 4-12
__device__ __forceinline__ void sort2048(u64* key, int tid, int lane, int wv) {
    const int base = wv * 512;
    for (int k = 2; k <= 512; k <<= 1)
        wave_rounds512(key, base, k, k >> 1, lane);
    __syncthreads();
    #pragma unroll
    for (int p = 0; p < 4; p++) {
        int r = tid + p * 256;
        int low = r & 511, high = (r & ~511) << 1;
        ce_desc(key, high | low, 512, 1024);
    }
    __syncthreads();
    wave_rounds512(key, base, 1024, 256, lane);
    __syncthreads();
    #pragma unroll
    for (int p = 0; p < 4; p++) {
        int r = tid + p * 256;
        int low = r & 1023, high = (r & ~1023) << 1;
        ce_desc(key, high | low, 1024, 2048);
    }
    __syncthreads();
    #pragma unroll
    for (int p = 0; p < 4; p++) {
        int r = tid + p * 256;
        int low = r & 511, high = (r & ~511) << 1;
        ce_desc(key, high | low, 512, 2048);
    }
    __syncthreads();
    wave_rounds512(key, base, 2048, 256, lane);
    __syncthreads();
}

// bitonic sort of 1024 (desc): 4 elems/thread, register-fused j<=2 rounds
__device__ __forceinline__ void sort1024(u64* a, int tid, int lane, int wv) {
    const int t4 = tid * 4;
    const int sb = wv * 256;
    {
        u64 v0 = a[t4], v1 = a[t4 + 1], v2 = a[t4 + 2], v3 = a[t4 + 3];
        ceg(v0, v1, true);
        ceg(v2, v3, false);
        const bool d4 = ((t4 & 4) == 0);
        ceg(v0, v2, d4); ceg(v1, v3, d4);
        ceg(v0, v1, d4); ceg(v2, v3, d4);
        a[t4] = v0; a[t4 + 1] = v1; a[t4 + 2] = v2; a[t4 + 3] = v3;
    }
    __builtin_amdgcn_wave_barrier();
    for (int k = 8; k <= 256; k <<= 1) {
        for (int j = k >> 1; j >= 4; j >>= 1) {
            #pragma unroll
            for (int p = 0; p < 2; p++) {
                int r = lane + p * 64;
                int low = r & (j - 1);
                int high = (r & ~(j - 1)) << 1;
                ce_desc(a, sb + (high | low), j, k);
            }
            __builtin_amdgcn_wave_barrier();
        }
        {
            u64 v0 = a[t4], v1 = a[t4 + 1], v2 = a[t4 + 2], v3 = a[t4 + 3];
            const bool d = ((t4 & k) == 0);
            ceg(v0, v2, d); ceg(v1, v3, d);
            ceg(v0, v1, d); ceg(v2, v3, d);
            a[t4] = v0; a[t4 + 1] = v1; a[t4 + 2] = v2; a[t4 + 3] = v3;
        }
        __builtin_amdgcn_wave_barrier();
    }
    __syncthreads();
    #pragma unroll
    for (int p = 0; p < 2; p++) {
        int r = tid + p * 256;
        int low = r & 255, high = (r & ~255) << 1;
        ce_desc(a, high | low, 256, 512);
    }
    __syncthreads();
    for (int j = 128; j >= 4; j >>= 1) {
        #pragma unroll
        for (int p = 0; p < 2; p++) {
            int r = lane + p * 64;
            int low = r & (j - 1);
            int high = (r & ~(j - 1)) << 1;
            ce_desc(a, sb + (high | low), j, 512);
        }
        __builtin_amdgcn_wave_barrier();
    }
    {
        u64 v0 = a[t4], v1 = a[t4 + 1], v2 = a[t4 + 2], v3 = a[t4 + 3];
        const bool d = ((t4 & 512) == 0);
        ceg(v0, v2, d); ceg(v1, v3, d);
        ceg(v0, v1, d); ceg(v2, v3, d);
        a[t4] = v0; a[t4 + 1] = v1; a[t4 + 2] = v2; a[t4 + 3] = v3;
    }
    __syncthreads();
    #pragma unroll
    for (int p = 0; p < 2; p++) {
        int r = tid + p * 256;
        int low = r & 511, high = (r & ~511) << 1;
        ce_desc(a, high | low, 512, 1024);
    }
    __syncthreads();
    #pragma unroll
    for (int p = 0; p < 2; p++) {
        int r = tid + p * 256;
        int low = r & 255, high = (r & ~255) << 1;
        ce_desc(a, high | low, 256, 1024);
    }
    __syncthreads();
    for (int j = 128; j >= 4; j >>= 1) {
        #pragma unroll
        for (int p = 0; p < 2; p++) {
            int r = lane + p * 64;
            int low = r & (j - 1);
            int high = (r & ~(j - 1)) << 1;
            ce_desc(a, sb + (high | low), j, 1024);
        }
        __builtin_amdgcn_wave_barrier();
    }
    {
        u64 v0 = a[t4], v1 = a[t4 + 1], v2 = a[t4 + 2], v3 = a[t4 + 3];
        const bool d = ((t4 & 1024) == 0);
        ceg(v0, v2, d); ceg(v1, v3, d);
        ceg(v0, v1, d); ceg(v2, v3, d);
        a[t4] = v0; a[t4 + 1] = v1; a[t4 + 2] = v2; a[t4 + 3] = v3;
    }
    __syncthreads();
}

// exact reference-order IoU > 0.5 test (byte-identical to passing rounds 3-13)
__device__ __forceinline__ bool iou_gt_half(float4 a, float aa, float4 b, float ab) {
    float ltx = fmaxf(a.x, b.x);
    float lty = fmaxf(a.y, b.y);
    float rbx = fminf(a.z, b.z);
    float rby = fminf(a.w, b.w);
    float wd = fmaxf(__fsub_rn(rbx, ltx), 0.0f);
    float hd = fmaxf(__fsub_rn(rby, lty), 0.0f);
    float inter = __fmul_rn(wd, hd);
    float uni = __fsub_rn(__fadd_rn(aa, ab), inter);
    float m = fmaxf(uni, 1e-8f);
    float d2 = __fmul_rn(2.0f, inter);
    bool sup = d2 > m;
    if (sup && (__fsub_rn(d2, m) <= __fmul_rn(m, 1.2e-7f)))
        sup = __fdiv_rn(inter, m) > IOU_T;
    return sup;
}

// bulk-gather boxes+areas of the first 1024 sorted candidates into LDS.
// Area computed with the exact same float ops as the greedy inline path.
__device__ __forceinline__ void prefetch1024(const u64* cand, const float* xb,
        float4* pbox, float* parea, int tid) {
    #pragma unroll
    for (int r = 0; r < 4; r++) {
        int i = r * 256 + tid;
        u64 k = cand[i];
        u32 orig = 2047u - (u32)(k & 0x7FFu);
        float4 bx = *(const float4*)(xb + (size_t)orig * ROW);
        pbox[i] = bx;
        parea[i] = __fmul_rn(__fsub_rn(bx.z, bx.x), __fsub_rn(bx.w, bx.y));
    }
    __syncthreads();
}

// wave-aggregated compaction push: 1 LDS atomic per wave instead of up to 64
// same-address serialized atomics. Placement order differs from the serial
// version but the selected key SET is identical and the following bitonic
// sort is placement-independent (keys unique), so results are bit-identical.
__device__ __forceinline__ void push_sel(u64* comp, u32* s_cnt, bool pred,
                                         u64 key, int lane) {
    u64 bal = __ballot(pred);
    u32 base = 0;
    if (lane == 0 && bal) base = atomicAdd(s_cnt, (u32)__popcll(bal));
    base = (u32)__shfl((int)base, 0, 64);
    if (pred) {
        u32 off = (u32)__popcll(bal & ((1ULL << lane) - 1ULL));
        comp[base + off] = key;
    }
}

// Chunked greedy over a desc-sorted array (low 11 bits = 2047-n).
// Per chunk, ALL 4 waves each compute (a) a 16-bit quarter of the in-chunk
// suppression column mask and (b) a stride-4 share of the tests vs
// previously-kept boxes. Serial sweep on wave 0 is pure mask algebra,
// stores deferred. IoU calls use identical operand order as the verified
// path; OR-reduction over identical test sets -> bit-identical decisions.
__device__ __forceinline__ int greedy(const u64* cand, int maxch, const float* xb,
        const float4* pbox, const float* parea,
        float4* s_cbox, float* s_car, u64* s_cm,
        float4* kept_box, float* kept_area, u64* kept_key,
        u64* s_sup, int* s_kept, int* s_done, int tid, int lane, int wv,
        int keptc_in) {
    if (tid == 0) { *s_kept = keptc_in; *s_done = 0; }
    __syncthreads();
    int keptc = keptc_in;
    for (int ch = 0; ch < maxch; ch++) {
        int n = ch * 64 + lane;
        u64 mykey = cand[n];
        float sc = __uint_as_float((u32)(mykey >> 32));
        bool valid = sc > SCORE_T;
        u64 vball = __ballot(valid);
        if (vball == 0ULL) break;

        float4 bx; float ar;
        const float4* cb; const float* ca;
        if (ch < 16) {
            bx = pbox[n];
            ar = parea[n];
            cb = pbox + ch * 64;
            ca = parea + ch * 64;
        } else {
            // fb path beyond the prefetched pool: stage chunk boxes for all
            // waves (each wave consumes them for its colmask quarter)
            u32 orig = 2047u - (u32)(mykey & 0x7FFu);
            bx = *(const float4*)(xb + (size_t)orig * ROW);
            ar = __fmul_rn(__fsub_rn(bx.z, bx.x), __fsub_rn(bx.w, bx.y));
            if (wv == 0) { s_cbox[lane] = bx; s_car[lane] = ar; }
            __syncthreads();
            cb = s_cbox; ca = s_car;
        }

        // (a) colmask quarter: j in [wv*16, wv*16+16)
        u64 cm = 0ULL;
        {
            const int j0 = wv * 16;
            #pragma unroll 4
            for (int jj = 0; jj < 16; jj++) {
                int j = j0 + jj;
                bool s = iou_gt_half(bx, ar, cb[j], ca[j]);
                cm |= ((u64)s) << j;
            }
            s_cm[wv * 64 + lane] = cm;
        }
        // (b) kept-tests, stride 4 offset wv (R12-verbatim distribution)
        {
            bool supA = false;
            int t = wv;
            for (; t + 12 < keptc; t += 16) {
                float4 kb0 = kept_box[t],     kb1 = kept_box[t + 4];
                float4 kb2 = kept_box[t + 8], kb3 = kept_box[t + 12];
                float ka0 = kept_area[t],     ka1 = kept_area[t + 4];
                float ka2 = kept_area[t + 8], ka3 = kept_area[t + 12];
                bool s0 = iou_gt_half(bx, ar, kb0, ka0);
                bool s1 = iou_gt_half(bx, ar, kb1, ka1);
                bool s2 = iou_gt_half(bx, ar, kb2, ka2);
                bool s3 = iou_gt_half(bx, ar, kb3, ka3);
                supA = supA | ((s0 | s1) | (s2 | s3));
            }
            for (; t < keptc; t += 4)
                supA = supA | iou_gt_half(bx, ar, kept_box[t], kept_area[t]);
            u64 supm = __ballot(supA);
            if (lane == 0) s_sup[wv] = supm;
        }
        __syncthreads();                   // B1

        if (wv == 0) {
            u64 colmask = cm | s_cm[64 + lane] | s_cm[128 + lane] | s_cm[192 + lane];
            u64 alive = vball & ~s_sup[0] & ~s_sup[1] & ~s_sup[2] & ~s_sup[3];
            int kept = keptc;
            u64 keptbits = 0ULL;
            int donef = 0;
            while (alive) {
                int bsel = (int)__builtin_ctzll(alive);
                keptbits |= 1ULL << bsel;
                kept++;
                if (kept >= OUT_K) { donef = 1; break; }
                alive &= alive - 1;
                if (!alive) break;
                alive &= ~__ballot(((colmask >> bsel) & 1ULL) != 0ULL);
            }
            // deferred parallel store; selection order == ascending lane order
            u32 rank = (u32)__popcll(keptbits & ((1ULL << lane) - 1ULL));
            if ((keptbits >> lane) & 1ULL) {
                int idx = keptc + (int)rank;
                kept_key[idx] = mykey;
                kept_box[idx] = bx;
                kept_area[idx] = ar;
            }
            if (lane == 0) { *s_kept = kept; if (donef) *s_done = 1; }
        }
        __syncthreads();                   // B2
        keptc = *s_kept;
        if (*s_done) break;
        if (__popcll(vball) < 64) break;
    }
    __syncthreads();
    return keptc;
}

// ---- Kernel T: coalesced transpose of scores into [B][C][N] ----
// 256 blocks x 256 threads; each block stages 64 rows (84 floats) in LDS
// (row stride 85: gcd(21,32)=1 -> conflict-free col reads)
__global__ __launch_bounds__(256) void transpose_kernel(
        const float* __restrict__ x, float* __restrict__ st) {
    const int t = blockIdx.x;
    const int b = t >> 5;
    const int rb = t & 31;
    const int tid = threadIdx.x;
    __shared__ float lds[64 * 85];

    const float* src = x + ((size_t)b * NN + (size_t)rb * 64) * ROW;
    #pragma unroll
    for (int q = 0; q < 6; q++) {
        int i4 = q * 256 + tid;
        if (i4 < 1344) {
            float4 v = *(const float4*)(src + (size_t)i4 * 4);
            int r = i4 / 21;
            int kq = (i4 % 21) * 4;
            float* d = lds + r * 85 + kq;
            d[0] = v.x; d[1] = v.y; d[2] = v.z; d[3] = v.w;
        }
    }
    __syncthreads();
    const int n0 = rb * 64;
    #pragma unroll
    for (int q = 0; q < 20; q++) {
        int j = q * 256 + tid;
        int c = j >> 6;
        int r = j & 63;
        st[(size_t)(b * NC + c) * NN + n0 + r] = lds[r * 85 + 4 + c];
    }
}

// ---- Kernel A: histogram-select -> sort1024 -> prefetch -> greedy ----
__global__ __launch_bounds__(256) void nms_kernel(
        const float* __restrict__ x, const float* __restrict__ scores_t,
        u64* __restrict__ cand_key) {
    const int bc = blockIdx.x;
    const int b = bc / NC;
    const int c = bc % NC;
    const int tid = threadIdx.x;
    const int lane = tid & 63;
    const int wv = tid >> 6;

    __shared__ __align__(16) u64 arr[2048];
    u64* comp = arr;
    u32* hist = (u32*)(arr + 1024);
    __shared__ __align__(16) float4 s_pbox[1024];
    __shared__ float s_parea[1024];
    __shared__ __align__(16) float4 s_cbox[64];
    __shared__ float s_car[64];
    __shared__ u64 s_cm[256];
    __shared__ float4 kept_box[OUT_K];
    __shared__ float kept_area[OUT_K];
    __shared__ u64 kept_key[OUT_K];
    __shared__ u64 s_sup[4];
    __shared__ u32 s_wsum[4];
    __shared__ u32 s_cnt, s_m;
    __shared__ int s_kept, s_done, s_thr;

    const float* xb = x + (size_t)b * NN * ROW;
    const float* sct = scores_t + (size_t)(b * NC + c) * NN;

    hist[tid] = 0;
    __syncthreads();
    // vectorized score load: 2 x float4 per thread; n = tid*8 + w
    // (bijective remap; selected key SET unchanged -> sort normalizes)
    float scv[8];
    {
        const float4* s4 = (const float4*)sct;
        float4 va = s4[tid * 2];
        float4 vb = s4[tid * 2 + 1];
        scv[0] = va.x; scv[1] = va.y; scv[2] = va.z; scv[3] = va.w;
        scv[4] = vb.x; scv[5] = vb.y; scv[6] = vb.z; scv[7] = vb.w;
    }
    #pragma unroll
    for (int w = 0; w < 8; w++) {
        int bin = (int)(scv[w] * 256.0f); bin = bin > 255 ? 255 : bin;
        atomicAdd(&hist[bin], 1u);
    }
    __syncthreads();

    u32 cnt_mine = hist[tid];
    u32 incl = cnt_mine;
    #pragma unroll
    for (int off = 1; off < 64; off <<= 1) {
        u32 v = __shfl_down(incl, off, 64);
        if (lane + off < 64) incl += v;
    }
    if (lane == 0) s_wsum[wv] = incl;
    __syncthreads();
    u32 above = 0;
    #pragma unroll
    for (int w = 0; w < 4; w++) above += (w > wv) ? s_wsum[w] : 0;
    const u32 suf = incl + above;

    if (tid == 0) s_thr = 2;
    __syncthreads();
    if (suf >= TGT && suf - cnt_mine < TGT) s_thr = tid;
    __syncthreads();
    int t1 = s_thr;
    if (tid == t1) s_m = suf;
    __syncthreads();
    u32 m_tot = s_m;

    bool fb = (m_tot > POOL);
    int kept = 0;
    if (!fb) {
        if (tid == 0) s_cnt = 0;
        __syncthreads();
        #pragma unroll
        for (int w = 0; w < 8; w++) {
            float sc = scv[w];
            int bin = (int)(sc * 256.0f); bin = bin > 255 ? 255 : bin;
            int n = tid * 8 + w;
            u64 key = ((u64)__float_as_uint(sc) << 32) | (u64)(2047 - n);
            push_sel(comp, &s_cnt, bin >= t1, key, lane);
        }
        __syncthreads();
        for (int i = tid; i < POOL; i += 256) if (i >= (int)m_tot) comp[i] = 0ULL;
        __syncthreads();
        sort1024(comp, tid, lane, wv);
        prefetch1024(comp, xb, s_pbox, s_parea, tid);
        kept = greedy(comp, POOL / 64, xb, s_pbox, s_parea, s_cbox, s_car, s_cm,
                      kept_box, kept_area, kept_key,
                      s_sup, &s_kept, &s_done, tid, lane, wv, 0);

        while (kept < OUT_K && t1 > 2) {
            u32 T2 = m_tot + TGT;
            if (tid == 0) s_thr = 2;
            __syncthreads();
            if (suf >= T2 && suf - cnt_mine < T2) s_thr = tid;
            __syncthreads();
            int t2 = s_thr;
            if (tid == t2) s_m = suf;
            __syncthreads();
            u32 m2 = s_m;
            u32 size = m2 - m_tot;
            if (size == 0) break;
            if (size > POOL) { fb = true; break; }
            if (tid == 0) s_cnt = 0;
            __syncthreads();
            #pragma unroll
            for (int w = 0; w < 8; w++) {
                float sc = scv[w];
                int bin = (int)(sc * 256.0f); bin = bin > 255 ? 255 : bin;
                int n = tid * 8 + w;
                u64 key = ((u64)__float_as_uint(sc) << 32) | (u64)(2047 - n);
                push_sel(comp, &s_cnt, bin >= t2 && bin < t1, key, lane);
            }
            __syncthreads();
            for (int i = tid; i < POOL; i += 256) if (i >= (int)size) comp[i] = 0ULL;
            __syncthreads();
            sort1024(comp, tid, lane, wv);
            prefetch1024(comp, xb, s_pbox, s_parea, tid);
            kept = greedy(comp, POOL / 64, xb, s_pbox, s_parea, s_cbox, s_car, s_cm,
                          kept_box, kept_area, kept_key,
                          s_sup, &s_kept, &s_done, tid, lane, wv, kept);
            m_tot = m2; t1 = t2;
        }
    }
    if (fb) {
        __syncthreads();
        #pragma unroll
        for (int w = 0; w < 8; w++) {
            int n = tid * 8 + w;
            arr[n] = ((u64)__float_as_uint(scv[w]) << 32) | (u64)(2047 - n);
        }
        __syncthreads();
        sort2048(arr, tid, lane, wv);
        prefetch1024(arr, xb, s_pbox, s_parea, tid);
        kept = greedy(arr, 32, xb, s_pbox, s_parea, s_cbox, s_car, s_cm,
                      kept_box, kept_area, kept_key,
                      s_sup, &s_kept, &s_done, tid, lane, wv, 0);
    }

    const int base_o = bc * OUT_K;
    if (tid < OUT_K) {
        u64 ok = 0ULL;
        if (tid < kept) {
            u64 kk = kept_key[tid];
            u32 flat = (u32)(c * OUT_K + tid);
            u32 orig = 2047u - (u32)(kk & 0x7FFu);
            ok = (kk & 0xFFFFFFFF00000000ULL) |
                 ((u64)(0x3FFFu - flat) << 11) | (u64)orig;
        }
        cand_key[base_o + tid] = ok;
    }
}

// ---- Kernel B1: 80 blocks x 256 threads. Each block tree-merges its 8 runs
//      of 200 and writes top-256 in place into its block-owned region. ----
__global__ __launch_bounds__(256) void merge8_kernel(u64* __restrict__ cand_key) {
    const int blk = blockIdx.x;          // 0..79
    const int b = blk / 10;
    const int g = blk % 10;
    const int tid = threadIdx.x;
    const int lane = tid & 63;
    const int wv = tid >> 6;
    __shared__ __align__(16) u64 seg[2048];

    u64* src = cand_key + (size_t)(b * NC + g * 8) * OUT_K;

    #pragma unroll
    for (int q = 0; q < 8; q++) {
        seg[q * 256 + tid] = (tid < OUT_K) ? src[q * OUT_K + tid] : 0ULL;
    }
    __syncthreads();
    pair_merge256(seg, wv * 512, 256, lane);
    __syncthreads();
    if (wv < 2) pair_merge256(seg, wv * 1024, 512, lane);
    __syncthreads();
    if (wv == 0) pair_merge256(seg, 0, 1024, lane);
    __syncthreads();
    src[tid] = seg[tid];
}

// ---- Kernel B2: 8 blocks x 256 threads. Merge the batch's 10 surviving
//      256-runs (depth-4 tree), decode top-200. ----
__global__ __launch_bounds__(256) void final_kernel(
        const float* __restrict__ x, const u64* __restrict__ cand_key,
        float* __restrict__ out) {
    const int b = blockIdx.x;
    const int tid = threadIdx.x;
    const int lane = tid & 63;
    const int wv = tid >> 6;
    __shared__ __align__(16) u64 seg[2560];

    #pragma unroll
    for (int q = 0; q < 10; q++) {
        seg[q * 256 + tid] = cand_key[(size_t)(b * NC + q * 8) * OUT_K + tid];
    }
    __syncthreads();
    pair_merge256(seg, wv * 512, 256, lane);
    __syncthreads();
    if (wv == 0) pair_merge256(seg, 0, 512, lane);
    else if (wv == 1) pair_merge256(seg, 1024, 512, lane);
    else if (wv == 2) pair_merge256(seg, 2048, 256, lane);
    __syncthreads();
    if (wv == 0) pair_merge256(seg, 0, 1024, lane);
    __syncthreads();
    if (wv == 0) pair_merge256(seg, 0, 2048, lane);
    __syncthreads();

    const float* xb = x + (size_t)b * NN * ROW;
    if (tid < OUT_K) {
        u64 kk = seg[tid];
        float* o = out + ((size_t)b * OUT_K + tid) * 6;
        if (kk == 0ULL) {
            o[0] = 0.f; o[1] = 0.f; o[2] = 0.f; o[3] = 0.f; o[4] = 0.f; o[5] = 0.f;
        } else {
            u32 lo = (u32)(kk & 0xFFFFFFFFu);
            u32 flat = 0x3FFFu - ((lo >> 11) & 0x3FFFu);
            int cls = flat / OUT_K;
            u32 n = lo & 0x7FFu;
            float scf = __uint_as_float((u32)(kk >> 32));
            float4 bx = *(const float4*)(xb + (size_t)n * ROW);
            o[0] = (float)cls;
            o[1] = scf;
            o[2] = fminf(fmaxf(bx.x, 0.0f), 1.0f);
            o[3] = fminf(fmaxf(bx.y, 0.0f), 1.0f);
            o[4] = fminf(fmaxf(bx.z, 0.0f), 1.0f);
            o[5] = fminf(fmaxf(bx.w, 0.0f), 1.0f);
        }
    }
}

extern "C" void kernel_launch(void* const* d_in, const int* in_sizes, int n_in,
                              void* d_out, int out_size, void* d_ws, size_t ws_size,
                              hipStream_t stream) {
    const float* x = (const float*)d_in[0];
    float* out = (float*)d_out;
    u64* cand_key = (u64*)d_ws;                            // 1,024,000 B
    float* scores_t = (float*)((char*)d_ws + 1024 * 1024); // 5,242,880 B
    transpose_kernel<<<NB * 32, 256, 0, stream>>>(x, scores_t);
    nms_kernel<<<NB * NC, 256, 0, stream>>>(x, scores_t, cand_key);
    merge8_kernel<<<NB * 10, 256, 0, stream>>>(cand_key);
    final_kernel<<<NB, 256, 0, stream>>>(x, cand_key, out);
}